// Round 1
// baseline (9515.733 us; speedup 1.0000x reference)
//
#include <hip/hip_runtime.h>
#include <stdint.h>

typedef unsigned short ushort_t;
typedef __attribute__((ext_vector_type(8))) short short8;      // 8 bf16 (4 VGPRs)
typedef __attribute__((ext_vector_type(4))) float f32x4;       // MFMA 16x16 acc
typedef __attribute__((ext_vector_type(4))) float float4v;
typedef __attribute__((ext_vector_type(4))) unsigned short ushort4v;
typedef __attribute__((ext_vector_type(4))) unsigned int uint4v;

#define NB 64
#define NT 512
#define ND 1024
#define NHH 1024
#define NG 4096

__device__ __forceinline__ ushort_t f2bf(float x) {
    uint32_t u = __builtin_bit_cast(uint32_t, x);
    u += 0x7fffu + ((u >> 16) & 1u);   // RTNE
    return (ushort_t)(u >> 16);
}
__device__ __forceinline__ float bf2f(ushort_t b) {
    uint32_t u = ((uint32_t)b) << 16;
    return __builtin_bit_cast(float, u);
}
__device__ __forceinline__ float fsigmoid(float x) { return 1.f / (1.f + __expf(-x)); }
__device__ __forceinline__ float ftanh(float x) {
    float ax = __builtin_fabsf(x);
    float e = __expf(-2.f * ax);
    float r = (1.f - e) / (1.f + e);
    return x < 0.f ? -r : r;
}
__device__ __forceinline__ float xg_load(const float* p) { return *p; }
__device__ __forceinline__ float xg_load(const ushort_t* p) { return bf2f(*p); }
__device__ __forceinline__ void xg_store(float* p, float v) { *p = v; }
__device__ __forceinline__ void xg_store(ushort_t* p, float v) { *p = f2bf(v); }

// ---------------- prep: fp32->bf16 conversions, zero h buffers, zero barrier counter
__global__ __launch_bounds__(256) void k_prep(
    const float* __restrict__ feat, const float* __restrict__ wih,
    const float* __restrict__ whh,
    ushort_t* __restrict__ featb, ushort_t* __restrict__ wihb,
    ushort_t* __restrict__ whhb, ushort_t* __restrict__ hbuf,
    int* __restrict__ cnt)
{
    const size_t NF = (size_t)NB * NT * ND / 4;   // 8388608 float4 chunks
    const size_t NW = (size_t)NG * ND / 4;        // 1048576
    const size_t NHB = (size_t)2 * 65536 * 2 / 16; // 16384 16B chunks
    size_t total = NF + 2 * NW + NHB;
    size_t stride = (size_t)gridDim.x * blockDim.x;
    for (size_t i = (size_t)blockIdx.x * blockDim.x + threadIdx.x; i < total; i += stride) {
        if (i < NF) {
            float4v v = ((const float4v*)feat)[i];
            ushort4v o = { f2bf(v[0]), f2bf(v[1]), f2bf(v[2]), f2bf(v[3]) };
            ((ushort4v*)featb)[i] = o;
        } else if (i < NF + NW) {
            size_t j = i - NF;
            float4v v = ((const float4v*)wih)[j];
            ushort4v o = { f2bf(v[0]), f2bf(v[1]), f2bf(v[2]), f2bf(v[3]) };
            ((ushort4v*)wihb)[j] = o;
        } else if (i < NF + 2 * NW) {
            size_t j = i - NF - NW;
            float4v v = ((const float4v*)whh)[j];
            ushort4v o = { f2bf(v[0]), f2bf(v[1]), f2bf(v[2]), f2bf(v[3]) };
            ((ushort4v*)whhb)[j] = o;
        } else {
            size_t j = i - NF - 2 * NW;
            uint4v z = { 0u, 0u, 0u, 0u };
            ((uint4v*)hbuf)[j] = z;
        }
    }
    if (blockIdx.x == 0 && threadIdx.x == 0) *cnt = 0;
}

// ---------------- x_gates GEMM: xg[t][b][g] = feat[b,t,:] . Wih[g,:] + (bih+bhh)[g]
// 128x128 tile, BK=64, 256 threads (4 waves, each 64x64 = 4x4 mfma 16x16x32 tiles)
template <typename XGT>
__global__ __launch_bounds__(256) void k_gemm(
    const ushort_t* __restrict__ Ab,   // feature bf16 [32768][1024]
    const ushort_t* __restrict__ Bb,   // W_ih bf16 [4096][1024]
    const float* __restrict__ bih, const float* __restrict__ bhh,
    const int* __restrict__ slenp, XGT* __restrict__ xg)
{
    int bid = blockIdx.x;                  // 8192 tiles
    int panel = bid >> 8;                  // 32 panels of (8 mt x 32 nt) for L2 reuse
    int qq = bid & 255;
    int mt = (panel << 3) | (qq & 7);
    int nt = qq >> 3;
    int m0 = mt << 7, n0 = nt << 7;
    int b = m0 >> 9;                       // 128-row tile lies within one batch
    int t0 = m0 & 511;
    int sl = slenp[b];
    if (t0 >= sl) return;                  // whole tile masked: xg never read there

    __shared__ ushort_t ldsA[8 * 129 * 8]; // [kblk8][row 128+1 pad][8] bf16
    __shared__ ushort_t ldsB[8 * 129 * 8];
    short8* sA = (short8*)ldsA;
    short8* sB = (short8*)ldsB;
    const short8* gA = (const short8*)Ab + (size_t)m0 * 128;
    const short8* gB = (const short8*)Bb + (size_t)n0 * 128;

    int tid = threadIdx.x;
    int wave = tid >> 6, lane = tid & 63;
    int wm = (wave >> 1) << 6;
    int wn = (wave & 1) << 6;
    int fl = lane & 15, fq = lane >> 4;

    f32x4 acc[4][4];
#pragma unroll
    for (int i = 0; i < 4; i++)
#pragma unroll
        for (int j = 0; j < 4; j++) { f32x4 z = {0.f, 0.f, 0.f, 0.f}; acc[i][j] = z; }

    int row_[4], kb_[4], c_[4];
#pragma unroll
    for (int u = 0; u < 4; u++) { int c = u * 256 + tid; c_[u] = c; row_[u] = c >> 3; kb_[u] = c & 7; }

    for (int k0 = 0; k0 < 128; k0 += 8) {  // k0 in short8 units; 16 iters of BK=64
        short8 va[4], vb[4];
#pragma unroll
        for (int u = 0; u < 4; u++) {
            va[u] = gA[(size_t)row_[u] * 128 + k0 + kb_[u]];
            vb[u] = gB[(size_t)row_[u] * 128 + k0 + kb_[u]];
        }
        __syncthreads();
#pragma unroll
        for (int u = 0; u < 4; u++) {
            sA[kb_[u] * 129 + row_[u]] = va[u];
            sB[kb_[u] * 129 + row_[u]] = vb[u];
        }
        __syncthreads();
#pragma unroll
        for (int ks = 0; ks < 2; ks++) {
            short8 af[4], bf[4];
#pragma unroll
            for (int i = 0; i < 4; i++) {
                af[i] = sA[(ks * 4 + fq) * 129 + wm + i * 16 + fl];
                bf[i] = sB[(ks * 4 + fq) * 129 + wn + i * 16 + fl];
            }
#pragma unroll
            for (int i = 0; i < 4; i++)
#pragma unroll
                for (int j = 0; j < 4; j++)
                    acc[i][j] = __builtin_amdgcn_mfma_f32_16x16x32_bf16(af[i], bf[j], acc[i][j], 0, 0, 0);
        }
    }
    // epilogue: C layout col=lane&15, row=quad*4+reg. Store to xg[t][b][g], masked rows.
#pragma unroll
    for (int j = 0; j < 4; j++) {
        int g = n0 + wn + j * 16 + fl;
        float bv = bih[g] + bhh[g];
#pragma unroll
        for (int i = 0; i < 4; i++) {
#pragma unroll
            for (int r = 0; r < 4; r++) {
                int m = wm + i * 16 + fq * 4 + r;
                int t = t0 + m;
                if (t < sl)
                    xg_store(&xg[((size_t)t * 64 + b) * 4096 + g], acc[i][j][r] + bv);
            }
        }
    }
}

// ---------------- persistent recurrence kernel: 256 WGs x 256 thr, one grid barrier/step
// WG = (mb: 16-batch block) x (j0: 16 h-columns). wave w = gate w, W rows in VGPRs.
// h buffers (bf16) swizzled [kblk128][b64][8] so A-frag loads are 16B/lane coalesced.
template <typename XGT>
__global__ __launch_bounds__(256, 1) void k_rec(
    const ushort_t* __restrict__ whhb, const XGT* __restrict__ xg,
    const int* __restrict__ slenp, ushort_t* __restrict__ hbuf,
    float* __restrict__ out, int* __restrict__ cnt)
{
    const int tid = threadIdx.x;
    const int wave = tid >> 6, lane = tid & 63;
    const int wg = blockIdx.x;
    const int mb = wg >> 6;            // 0..3
    const int j0 = (wg & 63) << 4;     // 16 j per WG
    const int nn = lane & 15, q = lane >> 4;

    // B-fragments: wave's 16 W_hh rows (gate=wave), all K=1024, resident in VGPRs
    short8 wfrag[32];
    {
        const short8* wp = (const short8*)whhb + (size_t)(wave * NHH + j0 + nn) * 128;
#pragma unroll
        for (int kk = 0; kk < 32; kk++) wfrag[kk] = wp[kk * 4 + q];
    }
    const int eb = tid >> 4, ej = tid & 15;
    const int b_g = (mb << 4) + eb;    // epilogue thread's (batch, j)
    const int j_g = j0 + ej;
    const int slen = slenp[b_g];
    const int blk_len = slenp[mb << 4]; // seq_len sorted desc -> block max
    const int ab = (mb << 4) + nn;     // A-frag batch row for this lane

    __shared__ float glds[16 * 68];    // gate tile transpose, padded stride 68

    float c_st = 0.f, h_st = 0.f;
    float xi = 0.f, xf = 0.f, xgv = 0.f, xo = 0.f;
    if (0 < slen) {
        size_t base = (size_t)b_g * 4096 + j_g;
        xi = xg_load(&xg[base]);        xf = xg_load(&xg[base + 1024]);
        xgv = xg_load(&xg[base + 2048]); xo = xg_load(&xg[base + 3072]);
    }

#pragma unroll 1
    for (int t = 0; t < NT; ++t) {
        bool blk_active = (t < blk_len);
        if (blk_active) {
            const short8* hb = (const short8*)(hbuf + (size_t)(t & 1) * 65536);
            f32x4 a0 = {0.f,0.f,0.f,0.f}, a1 = a0, a2 = a0, a3 = a0;
#pragma unroll
            for (int kk = 0; kk < 32; kk += 4) {
                short8 f0 = hb[(size_t)((kk + 0) * 4 + q) * 64 + ab];
                short8 f1 = hb[(size_t)((kk + 1) * 4 + q) * 64 + ab];
                short8 f2 = hb[(size_t)((kk + 2) * 4 + q) * 64 + ab];
                short8 f3 = hb[(size_t)((kk + 3) * 4 + q) * 64 + ab];
                a0 = __builtin_amdgcn_mfma_f32_16x16x32_bf16(f0, wfrag[kk + 0], a0, 0, 0, 0);
                a1 = __builtin_amdgcn_mfma_f32_16x16x32_bf16(f1, wfrag[kk + 1], a1, 0, 0, 0);
                a2 = __builtin_amdgcn_mfma_f32_16x16x32_bf16(f2, wfrag[kk + 2], a2, 0, 0, 0);
                a3 = __builtin_amdgcn_mfma_f32_16x16x32_bf16(f3, wfrag[kk + 3], a3, 0, 0, 0);
            }
            f32x4 gsum = (a0 + a1) + (a2 + a3);
            __syncthreads();
#pragma unroll
            for (int r = 0; r < 4; r++)
                glds[(q * 4 + r) * 68 + (wave << 4) + nn] = gsum[r];
            __syncthreads();
        }
        float hv = 0.f;
        if (t < slen) {                 // t<slen implies blk_active
            float ip = glds[eb * 68 + ej] + xi;
            float fp = glds[eb * 68 + 16 + ej] + xf;
            float gp = glds[eb * 68 + 32 + ej] + xgv;
            float op = glds[eb * 68 + 48 + ej] + xo;
            float i_s = fsigmoid(ip), f_s = fsigmoid(fp);
            float g_t = ftanh(gp), o_s = fsigmoid(op);
            float cn = __builtin_fmaf(f_s, c_st, i_s * g_t);
            c_st = cn;
            h_st = o_s * ftanh(cn);
            hv = h_st;
        }
        out[((size_t)b_g * NT + t) * 1024 + j_g] = hv;   // 0 past seq_len
        hbuf[(size_t)((t + 1) & 1) * 65536 + (size_t)((j_g >> 3) * 64 + b_g) * 8 + (j_g & 7)] = f2bf(h_st);
        // prefetch next step's xg (independent of h; overlaps barrier)
        xi = xf = xgv = xo = 0.f;
        if (t + 1 < slen) {
            size_t base = ((size_t)(t + 1) * 64 + b_g) * 4096 + j_g;
            xi = xg_load(&xg[base]);        xf = xg_load(&xg[base + 1024]);
            xgv = xg_load(&xg[base + 2048]); xo = xg_load(&xg[base + 3072]);
        }
        if (t != NT - 1) {
            __syncthreads();
            if (tid == 0) {
                __hip_atomic_fetch_add(cnt, 1, __ATOMIC_RELEASE, __HIP_MEMORY_SCOPE_AGENT);
                const int target = (t + 1) << 8;   // 256*(t+1)
                while (__hip_atomic_load(cnt, __ATOMIC_ACQUIRE, __HIP_MEMORY_SCOPE_AGENT) < target)
                    __builtin_amdgcn_s_sleep(1);
            }
            __syncthreads();
        }
    }
}

extern "C" void kernel_launch(void* const* d_in, const int* in_sizes, int n_in,
                              void* d_out, int out_size, void* d_ws, size_t ws_size,
                              hipStream_t stream)
{
    const float* feat = (const float*)d_in[0];
    const float* wih  = (const float*)d_in[1];
    const float* whh  = (const float*)d_in[2];
    const float* bih  = (const float*)d_in[3];
    const float* bhh  = (const float*)d_in[4];
    const int*   sl   = (const int*)d_in[5];
    float* out = (float*)d_out;
    char* ws = (char*)d_ws;

    size_t off = 0;
    auto take = [&](size_t bytes) -> size_t {
        size_t o = off; off += (bytes + 255) & ~(size_t)255; return o;
    };
    size_t o_featb = take((size_t)NB * NT * ND * 2);  // 64 MiB
    size_t o_wihb  = take((size_t)NG * ND * 2);       // 8 MiB
    size_t o_whhb  = take((size_t)NG * ND * 2);       // 8 MiB
    size_t o_hbuf  = take((size_t)2 * 65536 * 2);     // 256 KiB (2 bf16 h buffers)
    size_t o_cnt   = take(256);
    size_t o_xg    = off;

    ushort_t* featb = (ushort_t*)(ws + o_featb);
    ushort_t* wihb  = (ushort_t*)(ws + o_wihb);
    ushort_t* whhb  = (ushort_t*)(ws + o_whhb);
    ushort_t* hbuf  = (ushort_t*)(ws + o_hbuf);
    int* cnt        = (int*)(ws + o_cnt);

    k_prep<<<2048, 256, 0, stream>>>(feat, wih, whh, featb, wihb, whhb, hbuf, cnt);

    size_t xg_elems = (size_t)NT * NB * NG;
    bool f32xg = (o_xg + xg_elems * 4) <= ws_size;    // prefer fp32 xg for accuracy
    if (f32xg) {
        float* xg = (float*)(ws + o_xg);
        k_gemm<float><<<8192, 256, 0, stream>>>(featb, wihb, bih, bhh, sl, xg);
        k_rec<float><<<256, 256, 0, stream>>>(whhb, xg, sl, hbuf, out, cnt);
    } else {
        ushort_t* xg = (ushort_t*)(ws + o_xg);
        k_gemm<ushort_t><<<8192, 256, 0, stream>>>(featb, wihb, bih, bhh, sl, xg);
        k_rec<ushort_t><<<256, 256, 0, stream>>>(whhb, xg, sl, hbuf, out, cnt);
    }
}

// Round 3
// 6233.240 us; speedup vs baseline: 1.5266x; 1.5266x over previous
//
#include <hip/hip_runtime.h>
#include <stdint.h>

typedef unsigned short ushort_t;
typedef unsigned long long ull_t;
typedef __attribute__((ext_vector_type(8))) short short8;      // 8 bf16 (4 VGPRs)
typedef __attribute__((ext_vector_type(2))) unsigned long long ull2;
typedef __attribute__((ext_vector_type(4))) float f32x4;       // MFMA 16x16 acc
typedef __attribute__((ext_vector_type(4))) float float4v;
typedef __attribute__((ext_vector_type(4))) unsigned short ushort4v;
typedef __attribute__((ext_vector_type(4))) unsigned int uint4v;

#define NB 64
#define NT 512
#define ND 1024
#define NHH 1024
#define NG 4096

__device__ __forceinline__ ushort_t f2bf(float x) {
    uint32_t u = __builtin_bit_cast(uint32_t, x);
    u += 0x7fffu + ((u >> 16) & 1u);   // RTNE
    return (ushort_t)(u >> 16);
}
__device__ __forceinline__ float bf2f(ushort_t b) {
    uint32_t u = ((uint32_t)b) << 16;
    return __builtin_bit_cast(float, u);
}
__device__ __forceinline__ float fsigmoid(float x) { return 1.f / (1.f + __expf(-x)); }
__device__ __forceinline__ float ftanh(float x) {
    float ax = __builtin_fabsf(x);
    float e = __expf(-2.f * ax);
    float r = (1.f - e) / (1.f + e);
    return x < 0.f ? -r : r;
}
__device__ __forceinline__ float xg_load(const float* p) { return *p; }
__device__ __forceinline__ float xg_load(const ushort_t* p) { return bf2f(*p); }
__device__ __forceinline__ void xg_store(float* p, float v) { *p = v; }
__device__ __forceinline__ void xg_store(ushort_t* p, float v) { *p = f2bf(v); }

// ---------------- prep: fp32->bf16 conversions, zero h buffers, zero barrier counters
__global__ __launch_bounds__(256) void k_prep(
    const float* __restrict__ feat, const float* __restrict__ wih,
    const float* __restrict__ whh,
    ushort_t* __restrict__ featb, ushort_t* __restrict__ wihb,
    ushort_t* __restrict__ whhb, ushort_t* __restrict__ hbuf,
    int* __restrict__ cnt)
{
    const size_t NF = (size_t)NB * NT * ND / 4;   // 8388608 float4 chunks
    const size_t NW = (size_t)NG * ND / 4;        // 1048576
    const size_t NHB = (size_t)2 * 65536 * 2 / 16; // 16384 16B chunks
    size_t total = NF + 2 * NW + NHB;
    size_t stride = (size_t)gridDim.x * blockDim.x;
    for (size_t i = (size_t)blockIdx.x * blockDim.x + threadIdx.x; i < total; i += stride) {
        if (i < NF) {
            float4v v = ((const float4v*)feat)[i];
            ushort4v o = { f2bf(v[0]), f2bf(v[1]), f2bf(v[2]), f2bf(v[3]) };
            ((ushort4v*)featb)[i] = o;
        } else if (i < NF + NW) {
            size_t j = i - NF;
            float4v v = ((const float4v*)wih)[j];
            ushort4v o = { f2bf(v[0]), f2bf(v[1]), f2bf(v[2]), f2bf(v[3]) };
            ((ushort4v*)wihb)[j] = o;
        } else if (i < NF + 2 * NW) {
            size_t j = i - NF - NW;
            float4v v = ((const float4v*)whh)[j];
            ushort4v o = { f2bf(v[0]), f2bf(v[1]), f2bf(v[2]), f2bf(v[3]) };
            ((ushort4v*)whhb)[j] = o;
        } else {
            size_t j = i - NF - 2 * NW;
            uint4v z = { 0u, 0u, 0u, 0u };
            ((uint4v*)hbuf)[j] = z;
        }
    }
    // Zero the FULL 1024-int barrier region (4 blocks x 256 threads).
    // Round-2 bug: `threadIdx.x < 1024` with 256-thread blocks left cnt[256..1023]
    // poisoned (0xAAAAAAAA) -> root counter negative -> deadlock on step 0.
    if (blockIdx.x < 4) cnt[blockIdx.x * 256 + threadIdx.x] = 0;
}

// ---------------- x_gates GEMM: xg[t][b][g] = feat[b,t,:] . Wih[g,:] + (bih+bhh)[g]
// 128x128 tile, BK=64, 256 threads (4 waves, each 64x64 = 4x4 mfma 16x16x32 tiles)
template <typename XGT>
__global__ __launch_bounds__(256) void k_gemm(
    const ushort_t* __restrict__ Ab,   // feature bf16 [32768][1024]
    const ushort_t* __restrict__ Bb,   // W_ih bf16 [4096][1024]
    const float* __restrict__ bih, const float* __restrict__ bhh,
    const int* __restrict__ slenp, XGT* __restrict__ xg)
{
    int bid = blockIdx.x;                  // 8192 tiles
    int panel = bid >> 8;                  // 32 panels of (8 mt x 32 nt) for L2 reuse
    int qq = bid & 255;
    int mt = (panel << 3) | (qq & 7);
    int nt = qq >> 3;
    int m0 = mt << 7, n0 = nt << 7;
    int b = m0 >> 9;                       // 128-row tile lies within one batch
    int t0 = m0 & 511;
    int sl = slenp[b];
    if (t0 >= sl) return;                  // whole tile masked: xg never read there

    __shared__ ushort_t ldsA[8 * 129 * 8]; // [kblk8][row 128+1 pad][8] bf16
    __shared__ ushort_t ldsB[8 * 129 * 8];
    short8* sA = (short8*)ldsA;
    short8* sB = (short8*)ldsB;
    const short8* gA = (const short8*)Ab + (size_t)m0 * 128;
    const short8* gB = (const short8*)Bb + (size_t)n0 * 128;

    int tid = threadIdx.x;
    int wave = tid >> 6, lane = tid & 63;
    int wm = (wave >> 1) << 6;
    int wn = (wave & 1) << 6;
    int fl = lane & 15, fq = lane >> 4;

    f32x4 acc[4][4];
#pragma unroll
    for (int i = 0; i < 4; i++)
#pragma unroll
        for (int j = 0; j < 4; j++) { f32x4 z = {0.f, 0.f, 0.f, 0.f}; acc[i][j] = z; }

    int row_[4], kb_[4];
#pragma unroll
    for (int u = 0; u < 4; u++) { int c = u * 256 + tid; row_[u] = c >> 3; kb_[u] = c & 7; }

    for (int k0 = 0; k0 < 128; k0 += 8) {  // k0 in short8 units; 16 iters of BK=64
        short8 va[4], vb[4];
#pragma unroll
        for (int u = 0; u < 4; u++) {
            va[u] = gA[(size_t)row_[u] * 128 + k0 + kb_[u]];
            vb[u] = gB[(size_t)row_[u] * 128 + k0 + kb_[u]];
        }
        __syncthreads();
#pragma unroll
        for (int u = 0; u < 4; u++) {
            sA[kb_[u] * 129 + row_[u]] = va[u];
            sB[kb_[u] * 129 + row_[u]] = vb[u];
        }
        __syncthreads();
#pragma unroll
        for (int ks = 0; ks < 2; ks++) {
            short8 af[4], bf[4];
#pragma unroll
            for (int i = 0; i < 4; i++) {
                af[i] = sA[(ks * 4 + fq) * 129 + wm + i * 16 + fl];
                bf[i] = sB[(ks * 4 + fq) * 129 + wn + i * 16 + fl];
            }
#pragma unroll
            for (int i = 0; i < 4; i++)
#pragma unroll
                for (int j = 0; j < 4; j++)
                    acc[i][j] = __builtin_amdgcn_mfma_f32_16x16x32_bf16(af[i], bf[j], acc[i][j], 0, 0, 0);
        }
    }
    // epilogue: C layout col=lane&15, row=quad*4+reg. Store to xg[t][b][g], masked rows.
#pragma unroll
    for (int j = 0; j < 4; j++) {
        int g = n0 + wn + j * 16 + fl;
        float bv = bih[g] + bhh[g];
#pragma unroll
        for (int i = 0; i < 4; i++) {
#pragma unroll
            for (int r = 0; r < 4; r++) {
                int m = wm + i * 16 + fq * 4 + r;
                int t = t0 + m;
                if (t < sl)
                    xg_store(&xg[((size_t)t * 64 + b) * 4096 + g], acc[i][j][r] + bv);
            }
        }
    }
}

// ---------------- persistent recurrence kernel: 256 WGs x 256 thr
// WG = (mb: 16-batch block) x (j0: 16 h-columns). wave w = gate w, W rows in VGPRs.
// h buffers (bf16) swizzled [kblk128][b64][8]; exchanged via device-scope (sc1)
// fine-grained relaxed atomics through the Infinity Cache -> NO per-step L2
// writeback/invalidate cache ops. Barrier: 2-level relaxed counter tree
// (16 groups of 16 -> root), producer drains vmcnt before arrival.
template <typename XGT>
__global__ __launch_bounds__(256, 1) void k_rec(
    const ushort_t* __restrict__ whhb, const XGT* __restrict__ xg,
    const int* __restrict__ slenp, ushort_t* __restrict__ hbuf,
    float* __restrict__ out, int* __restrict__ cnt)
{
    const int tid = threadIdx.x;
    const int wave = tid >> 6, lane = tid & 63;
    const int wg = blockIdx.x;
    const int mb = wg >> 6;            // 0..3
    const int j0 = (wg & 63) << 4;     // 16 j per WG
    const int nn = lane & 15, q = lane >> 4;

    // B-fragments: wave's 16 W_hh rows (gate=wave), all K=1024, resident in VGPRs
    short8 wfrag[32];
    {
        const short8* wp = (const short8*)whhb + (size_t)(wave * NHH + j0 + nn) * 128;
#pragma unroll
        for (int kk = 0; kk < 32; kk++) wfrag[kk] = wp[kk * 4 + q];
    }
    const int eb = tid >> 4, ej = tid & 15;
    const int b_g = (mb << 4) + eb;    // epilogue thread's (batch, j)
    const int j_g = j0 + ej;
    const int slen = slenp[b_g];
    const int blk_len = slenp[mb << 4]; // seq_len sorted desc -> block max
    const int ab = (mb << 4) + nn;     // A-frag batch row for this lane

    // barrier tree: group counters at cnt[(wg>>4)*32] (128B apart), root at cnt[512]
    int* gcnt = cnt + ((wg >> 4) * 32);
    int* root = cnt + 512;

    __shared__ float glds[16 * 68];    // gate tile transpose, padded stride 68

    float c_st = 0.f, h_st = 0.f;
    float xi = 0.f, xf = 0.f, xgv = 0.f, xo = 0.f;
    if (0 < slen) {
        size_t base = (size_t)b_g * 4096 + j_g;
        xi = xg_load(&xg[base]);        xf = xg_load(&xg[base + 1024]);
        xgv = xg_load(&xg[base + 2048]); xo = xg_load(&xg[base + 3072]);
    }
    const size_t h_out_idx = (size_t)((j_g >> 3) * 64 + b_g) * 8 + (j_g & 7);

#pragma unroll 1
    for (int t = 0; t < NT; ++t) {
        // prefetch next step's xg early: HBM latency hides under gemm + barrier
        float nxi = 0.f, nxf = 0.f, nxg = 0.f, nxo = 0.f;
        if (t + 1 < slen) {
            size_t base = ((size_t)(t + 1) * 64 + b_g) * 4096 + j_g;
            nxi = xg_load(&xg[base]);        nxf = xg_load(&xg[base + 1024]);
            nxg = xg_load(&xg[base + 2048]); nxo = xg_load(&xg[base + 3072]);
        }
        bool blk_active = (t < blk_len);
        if (blk_active) {
            const ull_t* hb8 = (const ull_t*)(hbuf + (size_t)(t & 1) * 65536);
            f32x4 a0 = {0.f,0.f,0.f,0.f}, a1 = a0, a2 = a0, a3 = a0;
#pragma unroll
            for (int kk = 0; kk < 32; kk += 4) {
#pragma unroll
                for (int u = 0; u < 4; u++) {
                    size_t a16 = (size_t)((kk + u) * 4 + q) * 64 + ab;
                    ull_t lo = __hip_atomic_load(&hb8[a16 * 2],     __ATOMIC_RELAXED, __HIP_MEMORY_SCOPE_AGENT);
                    ull_t hi = __hip_atomic_load(&hb8[a16 * 2 + 1], __ATOMIC_RELAXED, __HIP_MEMORY_SCOPE_AGENT);
                    ull2 p; p[0] = lo; p[1] = hi;
                    short8 f = __builtin_bit_cast(short8, p);
                    if (u == 0)      a0 = __builtin_amdgcn_mfma_f32_16x16x32_bf16(f, wfrag[kk + 0], a0, 0, 0, 0);
                    else if (u == 1) a1 = __builtin_amdgcn_mfma_f32_16x16x32_bf16(f, wfrag[kk + 1], a1, 0, 0, 0);
                    else if (u == 2) a2 = __builtin_amdgcn_mfma_f32_16x16x32_bf16(f, wfrag[kk + 2], a2, 0, 0, 0);
                    else             a3 = __builtin_amdgcn_mfma_f32_16x16x32_bf16(f, wfrag[kk + 3], a3, 0, 0, 0);
                }
            }
            f32x4 gsum = (a0 + a1) + (a2 + a3);
            __syncthreads();
#pragma unroll
            for (int r = 0; r < 4; r++)
                glds[(q * 4 + r) * 68 + (wave << 4) + nn] = gsum[r];
            __syncthreads();
        }
        float hv = 0.f;
        if (t < slen) {                 // t<slen implies blk_active
            float ip = glds[eb * 68 + ej] + xi;
            float fp = glds[eb * 68 + 16 + ej] + xf;
            float gp = glds[eb * 68 + 32 + ej] + xgv;
            float op = glds[eb * 68 + 48 + ej] + xo;
            float i_s = fsigmoid(ip), f_s = fsigmoid(fp);
            float g_t = ftanh(gp), o_s = fsigmoid(op);
            float cn = __builtin_fmaf(f_s, c_st, i_s * g_t);
            c_st = cn;
            h_st = o_s * ftanh(cn);
            hv = h_st;
        }
        out[((size_t)b_g * NT + t) * 1024 + j_g] = hv;   // 0 past seq_len
        // h store: device-scope fine-grained (sc1, visible at L3 once vmcnt drains)
        __hip_atomic_store(&hbuf[(size_t)((t + 1) & 1) * 65536 + h_out_idx], f2bf(h_st),
                           __ATOMIC_RELAXED, __HIP_MEMORY_SCOPE_AGENT);
        xi = nxi; xf = nxf; xgv = nxg; xo = nxo;
        if (t != NT - 1) {
            // every wave drains its own vmem (h store must be at L3 before arrival)
            asm volatile("s_waitcnt vmcnt(0)" ::: "memory");
            __syncthreads();
            if (tid == 0) {
                int old = __hip_atomic_fetch_add(gcnt, 1, __ATOMIC_RELAXED, __HIP_MEMORY_SCOPE_AGENT);
                if ((old & 15) == 15)   // last arrival of this 16-WG group this step
                    __hip_atomic_fetch_add(root, 1, __ATOMIC_RELAXED, __HIP_MEMORY_SCOPE_AGENT);
                const int target = (t + 1) << 4;   // root += 16 per step
                while (__hip_atomic_load(root, __ATOMIC_RELAXED, __HIP_MEMORY_SCOPE_AGENT) < target)
                    __builtin_amdgcn_s_sleep(2);
            }
            __syncthreads();
        }
    }
}

extern "C" void kernel_launch(void* const* d_in, const int* in_sizes, int n_in,
                              void* d_out, int out_size, void* d_ws, size_t ws_size,
                              hipStream_t stream)
{
    const float* feat = (const float*)d_in[0];
    const float* wih  = (const float*)d_in[1];
    const float* whh  = (const float*)d_in[2];
    const float* bih  = (const float*)d_in[3];
    const float* bhh  = (const float*)d_in[4];
    const int*   sl   = (const int*)d_in[5];
    float* out = (float*)d_out;
    char* ws = (char*)d_ws;

    size_t off = 0;
    auto take = [&](size_t bytes) -> size_t {
        size_t o = off; off += (bytes + 255) & ~(size_t)255; return o;
    };
    size_t o_featb = take((size_t)NB * NT * ND * 2);  // 64 MiB
    size_t o_wihb  = take((size_t)NG * ND * 2);       // 8 MiB
    size_t o_whhb  = take((size_t)NG * ND * 2);       // 8 MiB
    size_t o_hbuf  = take((size_t)2 * 65536 * 2);     // 256 KiB (2 bf16 h buffers)
    size_t o_cnt   = take(4096);                      // barrier tree (1024 ints)
    size_t o_xg    = off;

    ushort_t* featb = (ushort_t*)(ws + o_featb);
    ushort_t* wihb  = (ushort_t*)(ws + o_wihb);
    ushort_t* whhb  = (ushort_t*)(ws + o_whhb);
    ushort_t* hbuf  = (ushort_t*)(ws + o_hbuf);
    int* cnt        = (int*)(ws + o_cnt);

    k_prep<<<2048, 256, 0, stream>>>(feat, wih, whh, featb, wihb, whhb, hbuf, cnt);

    size_t xg_elems = (size_t)NT * NB * NG;
    bool f32xg = (o_xg + xg_elems * 4) <= ws_size;    // prefer fp32 xg for accuracy
    if (f32xg) {
        float* xg = (float*)(ws + o_xg);
        k_gemm<float><<<8192, 256, 0, stream>>>(featb, wihb, bih, bhh, sl, xg);
        k_rec<float><<<256, 256, 0, stream>>>(whhb, xg, sl, hbuf, out, cnt);
    } else {
        ushort_t* xg = (ushort_t*)(ws + o_xg);
        k_gemm<ushort_t><<<8192, 256, 0, stream>>>(featb, wihb, bih, bhh, sl, xg);
        k_rec<ushort_t><<<256, 256, 0, stream>>>(whhb, xg, sl, hbuf, out, cnt);
    }
}

// Round 4
// 2644.180 us; speedup vs baseline: 3.5987x; 2.3573x over previous
//
#include <hip/hip_runtime.h>
#include <stdint.h>

typedef unsigned short ushort_t;
typedef unsigned long long ull_t;
typedef __attribute__((ext_vector_type(8))) short short8;      // 8 bf16 (4 VGPRs)
typedef __attribute__((ext_vector_type(2))) unsigned long long ull2;
typedef __attribute__((ext_vector_type(4))) float f32x4;       // MFMA 16x16 acc
typedef __attribute__((ext_vector_type(4))) float float4v;
typedef __attribute__((ext_vector_type(4))) unsigned short ushort4v;
typedef __attribute__((ext_vector_type(4))) unsigned int uint4v;

#define NB 64
#define NT 512
#define ND 1024
#define NHH 1024
#define NG 4096

__device__ __forceinline__ ushort_t f2bf(float x) {
    uint32_t u = __builtin_bit_cast(uint32_t, x);
    u += 0x7fffu + ((u >> 16) & 1u);   // RTNE
    return (ushort_t)(u >> 16);
}
__device__ __forceinline__ float bf2f(ushort_t b) {
    uint32_t u = ((uint32_t)b) << 16;
    return __builtin_bit_cast(float, u);
}
__device__ __forceinline__ float fsigmoid(float x) { return 1.f / (1.f + __expf(-x)); }
__device__ __forceinline__ float ftanh(float x) {
    float ax = __builtin_fabsf(x);
    float e = __expf(-2.f * ax);
    float r = (1.f - e) / (1.f + e);
    return x < 0.f ? -r : r;
}
__device__ __forceinline__ void xg_store(float* p, float v) { *p = v; }
__device__ __forceinline__ void xg_store(ushort_t* p, float v) { *p = f2bf(v); }
__device__ __forceinline__ float4v xg_load4(const float4v* p) { return *p; }
__device__ __forceinline__ float4v xg_load4(const ushort4v* p) {
    ushort4v u = *p;
    float4v r = { bf2f(u[0]), bf2f(u[1]), bf2f(u[2]), bf2f(u[3]) };
    return r;
}

// ---------------- prep: fp32->bf16 conversions (W_ih row-PERMUTED: r' = j*4+gate
// so k_gemm's natural output layout is gate-interleaved float4), zero h buffers,
// zero barrier counters.
__global__ __launch_bounds__(256) void k_prep(
    const float* __restrict__ feat, const float* __restrict__ wih,
    const float* __restrict__ whh,
    ushort_t* __restrict__ featb, ushort_t* __restrict__ wihb,
    ushort_t* __restrict__ whhb, ushort_t* __restrict__ hbuf,
    int* __restrict__ cnt)
{
    const size_t NF = (size_t)NB * NT * ND / 4;   // 8388608 float4 chunks
    const size_t NW = (size_t)NG * ND / 4;        // 1048576
    const size_t NHB = (size_t)2 * 65536 * 2 / 16; // 16384 16B chunks
    size_t total = NF + 2 * NW + NHB;
    size_t stride = (size_t)gridDim.x * blockDim.x;
    for (size_t i = (size_t)blockIdx.x * blockDim.x + threadIdx.x; i < total; i += stride) {
        if (i < NF) {
            float4v v = ((const float4v*)feat)[i];
            ushort4v o = { f2bf(v[0]), f2bf(v[1]), f2bf(v[2]), f2bf(v[3]) };
            ((ushort4v*)featb)[i] = o;
        } else if (i < NF + NW) {
            size_t j = i - NF;                      // chunk over [4096 rows][256 f4]
            size_t row = j >> 8, kc = j & 255;
            size_t rowp = ((row & 1023) << 2) | (row >> 10);   // j*4 + gate
            float4v v = ((const float4v*)wih)[j];
            ushort4v o = { f2bf(v[0]), f2bf(v[1]), f2bf(v[2]), f2bf(v[3]) };
            ((ushort4v*)wihb)[rowp * 256 + kc] = o;
        } else if (i < NF + 2 * NW) {
            size_t j = i - NF - NW;
            float4v v = ((const float4v*)whh)[j];
            ushort4v o = { f2bf(v[0]), f2bf(v[1]), f2bf(v[2]), f2bf(v[3]) };
            ((ushort4v*)whhb)[j] = o;
        } else {
            size_t j = i - NF - 2 * NW;
            uint4v z = { 0u, 0u, 0u, 0u };
            ((uint4v*)hbuf)[j] = z;
        }
    }
    // Zero the FULL 1024-int barrier region (4 blocks x 256 threads).
    if (blockIdx.x < 4) cnt[blockIdx.x * 256 + threadIdx.x] = 0;
}

// ---------------- x_gates GEMM: xg[t][b][rp] = feat[b,t,:] . Wih'[rp,:] + bias[rp]
// rp = j*4+gate (permuted). 128x128 tile, BK=64, 256 threads.
template <typename XGT>
__global__ __launch_bounds__(256) void k_gemm(
    const ushort_t* __restrict__ Ab,   // feature bf16 [32768][1024]
    const ushort_t* __restrict__ Bb,   // W_ih' bf16 [4096][1024] (row-permuted)
    const float* __restrict__ bih, const float* __restrict__ bhh,
    const int* __restrict__ slenp, XGT* __restrict__ xg)
{
    int bid = blockIdx.x;                  // 8192 tiles
    int panel = bid >> 8;                  // 32 panels of (8 mt x 32 nt) for L2 reuse
    int qq = bid & 255;
    int mt = (panel << 3) | (qq & 7);
    int nt = qq >> 3;
    int m0 = mt << 7, n0 = nt << 7;
    int b = m0 >> 9;                       // 128-row tile lies within one batch
    int t0 = m0 & 511;
    int sl = slenp[b];
    if (t0 >= sl) return;                  // whole tile masked: xg never read there

    __shared__ ushort_t ldsA[8 * 129 * 8]; // [kblk8][row 128+1 pad][8] bf16
    __shared__ ushort_t ldsB[8 * 129 * 8];
    short8* sA = (short8*)ldsA;
    short8* sB = (short8*)ldsB;
    const short8* gA = (const short8*)Ab + (size_t)m0 * 128;
    const short8* gB = (const short8*)Bb + (size_t)n0 * 128;

    int tid = threadIdx.x;
    int wave = tid >> 6, lane = tid & 63;
    int wm = (wave >> 1) << 6;
    int wn = (wave & 1) << 6;
    int fl = lane & 15, fq = lane >> 4;

    f32x4 acc[4][4];
#pragma unroll
    for (int i = 0; i < 4; i++)
#pragma unroll
        for (int j = 0; j < 4; j++) { f32x4 z = {0.f, 0.f, 0.f, 0.f}; acc[i][j] = z; }

    int row_[4], kb_[4];
#pragma unroll
    for (int u = 0; u < 4; u++) { int c = u * 256 + tid; row_[u] = c >> 3; kb_[u] = c & 7; }

    for (int k0 = 0; k0 < 128; k0 += 8) {  // k0 in short8 units; 16 iters of BK=64
        short8 va[4], vb[4];
#pragma unroll
        for (int u = 0; u < 4; u++) {
            va[u] = gA[(size_t)row_[u] * 128 + k0 + kb_[u]];
            vb[u] = gB[(size_t)row_[u] * 128 + k0 + kb_[u]];
        }
        __syncthreads();
#pragma unroll
        for (int u = 0; u < 4; u++) {
            sA[kb_[u] * 129 + row_[u]] = va[u];
            sB[kb_[u] * 129 + row_[u]] = vb[u];
        }
        __syncthreads();
#pragma unroll
        for (int ks = 0; ks < 2; ks++) {
            short8 af[4], bf[4];
#pragma unroll
            for (int i = 0; i < 4; i++) {
                af[i] = sA[(ks * 4 + fq) * 129 + wm + i * 16 + fl];
                bf[i] = sB[(ks * 4 + fq) * 129 + wn + i * 16 + fl];
            }
#pragma unroll
            for (int i = 0; i < 4; i++)
#pragma unroll
                for (int j = 0; j < 4; j++)
                    acc[i][j] = __builtin_amdgcn_mfma_f32_16x16x32_bf16(af[i], bf[j], acc[i][j], 0, 0, 0);
        }
    }
    // epilogue: C layout col=lane&15, row=quad*4+reg. Columns are permuted rows rp.
#pragma unroll
    for (int j = 0; j < 4; j++) {
        int rp = n0 + wn + j * 16 + fl;              // permuted row index
        int bi = ((rp & 3) << 10) | (rp >> 2);       // gate*1024 + j
        float bv = bih[bi] + bhh[bi];
#pragma unroll
        for (int i = 0; i < 4; i++) {
#pragma unroll
            for (int r = 0; r < 4; r++) {
                int m = wm + i * 16 + fq * 4 + r;
                int t = t0 + m;
                if (t < sl)
                    xg_store(&xg[((size_t)t * 64 + b) * 4096 + rp], acc[i][j][r] + bv);
            }
        }
    }
}

// ---------------- persistent recurrence kernel: 256 WGs x 256 thr
// WG = (mb: 16-batch block) x (j0: 16 h-columns). Wave ks = K-quarter for ALL 4
// gates (B rows = 4g x 16j at 256k = 128 VGPRs). A-slices disjoint across waves
// -> h L3 traffic 8 MB/step (was 32). Cross-wave ks-reduction in padded LDS.
// Barrier: relaxed tree (16x16 -> root) + hierarchical flag broadcast.
template <typename XG4>
__global__ __launch_bounds__(256, 1) void k_rec(
    const ushort_t* __restrict__ whhb, const XG4* __restrict__ xg4,
    const int* __restrict__ slenp, ushort_t* __restrict__ hbuf,
    float* __restrict__ out, int* __restrict__ cnt)
{
    const int tid = threadIdx.x;
    const int ks = tid >> 6, lane = tid & 63;      // wave = K-quarter
    const int wg = blockIdx.x;
    const int mb = wg >> 6;            // 0..3
    const int j0 = (wg & 63) << 4;     // 16 j per WG
    const int nn = lane & 15, q = lane >> 4;

    // B-fragments: 4 gates x 16 j rows at K-quarter ks, resident in VGPRs (128)
    short8 wfrag[4][8];
    {
        const short8* w8 = (const short8*)whhb;
#pragma unroll
        for (int g = 0; g < 4; g++) {
            const short8* wp = w8 + (size_t)(g * NHH + j0 + nn) * 128 + ks * 32;
#pragma unroll
            for (int u = 0; u < 8; u++) wfrag[g][u] = wp[u * 4 + q];
        }
    }
    const int eb = tid >> 4, ej = tid & 15;
    const int b_g = (mb << 4) + eb;    // epilogue thread's (batch, j)
    const int j_g = j0 + ej;
    const int slen = slenp[b_g];
    const int blk_len = slenp[mb << 4]; // seq_len sorted desc -> block max
    const int ab = (mb << 4) + nn;     // A-frag batch row for this lane

    // barrier state: gcnt at cnt[(wg>>4)*32], root at cnt[512], flags at cnt[640+grp*16]
    int* gcnt = cnt + ((wg >> 4) * 32);
    int* root = cnt + 512;
    int* flag = cnt + 640 + ((wg >> 4) * 16);
    const bool leader = ((wg & 15) == 0);

    // ks-reduction buffer: [g][j 16][ks 4][b 16], j-stride 84 floats, ks-stride 20
    __shared__ float red[4 * 16 * 84];   // 21504 B

    float c_st = 0.f, h_st = 0.f, hv_prev = 0.f;

#pragma unroll 1
    for (int t = 0; t < NT; ++t) {
        // deferred out store for t-1 (drained by a LATER arrival, off critical path)
        if (t > 0) out[((size_t)b_g * NT + (t - 1)) * 1024 + j_g] = hv_prev;
        // xg(t) load: 1x16B coalesced; HBM latency hides under gemm phase
        float4v xv = { 0.f, 0.f, 0.f, 0.f };
        if (t < slen) xv = xg_load4(&xg4[((size_t)t * 64 + b_g) * 1024 + j_g]);

        bool blk_active = (t < blk_len);
        if (blk_active) {
            const ull_t* hb8 = (const ull_t*)(hbuf + (size_t)(t & 1) * 65536);
            // A: 8 x 16B agent loads (disjoint K-quarter per wave)
            ull_t raw[16];
#pragma unroll
            for (int u = 0; u < 8; u++) {
                size_t ch = ((size_t)((ks * 32 + u * 4 + q) * 64 + ab)) * 2;
                raw[2 * u]     = __hip_atomic_load(&hb8[ch],     __ATOMIC_RELAXED, __HIP_MEMORY_SCOPE_AGENT);
                raw[2 * u + 1] = __hip_atomic_load(&hb8[ch + 1], __ATOMIC_RELAXED, __HIP_MEMORY_SCOPE_AGENT);
            }
            f32x4 acc[4];
#pragma unroll
            for (int g = 0; g < 4; g++) { f32x4 z = {0.f, 0.f, 0.f, 0.f}; acc[g] = z; }
#pragma unroll
            for (int u = 0; u < 8; u++) {
                ull2 p; p[0] = raw[2 * u]; p[1] = raw[2 * u + 1];
                short8 af = __builtin_bit_cast(short8, p);
#pragma unroll
                for (int g = 0; g < 4; g++)
                    acc[g] = __builtin_amdgcn_mfma_f32_16x16x32_bf16(af, wfrag[g][u], acc[g], 0, 0, 0);
            }
            __syncthreads();   // red consumed last step (separated by grid barrier)
#pragma unroll
            for (int g = 0; g < 4; g++)
                *(f32x4*)&red[g * 1344 + nn * 84 + ks * 20 + q * 4] = acc[g];
            __syncthreads();
        }
        float hv = 0.f;
        if (t < slen) {                 // t<slen implies blk_active
            float s[4];
#pragma unroll
            for (int g = 0; g < 4; g++) {
                const float* rp = &red[g * 1344 + ej * 84 + eb];
                s[g] = (rp[0] + rp[20]) + (rp[40] + rp[60]);
            }
            float ip = s[0] + xv[0];
            float fp = s[1] + xv[1];
            float gp = s[2] + xv[2];
            float op = s[3] + xv[3];
            float i_s = fsigmoid(ip), f_s = fsigmoid(fp);
            float g_t = ftanh(gp), o_s = fsigmoid(op);
            float cn = __builtin_fmaf(f_s, c_st, i_s * g_t);
            c_st = cn;
            h_st = o_s * ftanh(cn);
            hv = h_st;
        }
        hv_prev = hv;
        // h store: device-scope fine-grained (visible at L3 once vmcnt drains)
        __hip_atomic_store(&hbuf[(size_t)((t + 1) & 1) * 65536 +
                                 (size_t)((j_g >> 3) * 64 + b_g) * 8 + (j_g & 7)],
                           f2bf(h_st), __ATOMIC_RELAXED, __HIP_MEMORY_SCOPE_AGENT);
        if (t != NT - 1) {
            // drain own vmem (h store must be at L3 before arrival)
            asm volatile("s_waitcnt vmcnt(0)" ::: "memory");
            __syncthreads();
            if (tid == 0) {
                int old = __hip_atomic_fetch_add(gcnt, 1, __ATOMIC_RELAXED, __HIP_MEMORY_SCOPE_AGENT);
                if ((old & 15) == 15)   // last arrival of this 16-WG group this step
                    __hip_atomic_fetch_add(root, 1, __ATOMIC_RELAXED, __HIP_MEMORY_SCOPE_AGENT);
                const int target = (t + 1) << 4;   // root += 16 per step
                if (leader) {
                    while (__hip_atomic_load(root, __ATOMIC_RELAXED, __HIP_MEMORY_SCOPE_AGENT) < target)
                        __builtin_amdgcn_s_sleep(2);
                    __hip_atomic_store(flag, t + 1, __ATOMIC_RELAXED, __HIP_MEMORY_SCOPE_AGENT);
                } else {
                    while (__hip_atomic_load(flag, __ATOMIC_RELAXED, __HIP_MEMORY_SCOPE_AGENT) < t + 1)
                        __builtin_amdgcn_s_sleep(2);
                }
            }
            __syncthreads();
        }
    }
    out[((size_t)b_g * NT + (NT - 1)) * 1024 + j_g] = hv_prev;
}

extern "C" void kernel_launch(void* const* d_in, const int* in_sizes, int n_in,
                              void* d_out, int out_size, void* d_ws, size_t ws_size,
                              hipStream_t stream)
{
    const float* feat = (const float*)d_in[0];
    const float* wih  = (const float*)d_in[1];
    const float* whh  = (const float*)d_in[2];
    const float* bih  = (const float*)d_in[3];
    const float* bhh  = (const float*)d_in[4];
    const int*   sl   = (const int*)d_in[5];
    float* out = (float*)d_out;
    char* ws = (char*)d_ws;

    size_t off = 0;
    auto take = [&](size_t bytes) -> size_t {
        size_t o = off; off += (bytes + 255) & ~(size_t)255; return o;
    };
    size_t o_featb = take((size_t)NB * NT * ND * 2);  // 64 MiB
    size_t o_wihb  = take((size_t)NG * ND * 2);       // 8 MiB
    size_t o_whhb  = take((size_t)NG * ND * 2);       // 8 MiB
    size_t o_hbuf  = take((size_t)2 * 65536 * 2);     // 256 KiB (2 bf16 h buffers)
    size_t o_cnt   = take(4096);                      // barrier tree (1024 ints)
    size_t o_xg    = off;

    ushort_t* featb = (ushort_t*)(ws + o_featb);
    ushort_t* wihb  = (ushort_t*)(ws + o_wihb);
    ushort_t* whhb  = (ushort_t*)(ws + o_whhb);
    ushort_t* hbuf  = (ushort_t*)(ws + o_hbuf);
    int* cnt        = (int*)(ws + o_cnt);

    k_prep<<<2048, 256, 0, stream>>>(feat, wih, whh, featb, wihb, whhb, hbuf, cnt);

    size_t xg_elems = (size_t)NT * NB * NG;
    bool f32xg = (o_xg + xg_elems * 4) <= ws_size;    // prefer fp32 xg for accuracy
    if (f32xg) {
        float* xg = (float*)(ws + o_xg);
        k_gemm<float><<<8192, 256, 0, stream>>>(featb, wihb, bih, bhh, sl, xg);
        k_rec<float4v><<<256, 256, 0, stream>>>(whhb, (const float4v*)xg, sl, hbuf, out, cnt);
    } else {
        ushort_t* xg = (ushort_t*)(ws + o_xg);
        k_gemm<ushort_t><<<8192, 256, 0, stream>>>(featb, wihb, bih, bhh, sl, xg);
        k_rec<ushort4v><<<256, 256, 0, stream>>>(whhb, (const ushort4v*)xg, sl, hbuf, out, cnt);
    }
}

// Round 5
// 2607.931 us; speedup vs baseline: 3.6488x; 1.0139x over previous
//
#include <hip/hip_runtime.h>
#include <stdint.h>

typedef unsigned short ushort_t;
typedef unsigned long long ull_t;
typedef __attribute__((ext_vector_type(8))) short short8;      // 8 bf16 (4 VGPRs)
typedef __attribute__((ext_vector_type(2))) unsigned long long ull2;
typedef __attribute__((ext_vector_type(4))) float f32x4;       // MFMA 16x16 acc
typedef __attribute__((ext_vector_type(4))) float float4v;
typedef __attribute__((ext_vector_type(4))) unsigned short ushort4v;
typedef __attribute__((ext_vector_type(4))) unsigned int uint4v;

#define NB 64
#define NT 512
#define ND 1024
#define NHH 1024
#define NG 4096

__device__ __forceinline__ ushort_t f2bf(float x) {
    uint32_t u = __builtin_bit_cast(uint32_t, x);
    u += 0x7fffu + ((u >> 16) & 1u);   // RTNE
    return (ushort_t)(u >> 16);
}
__device__ __forceinline__ float bf2f(ushort_t b) {
    uint32_t u = ((uint32_t)b) << 16;
    return __builtin_bit_cast(float, u);
}
__device__ __forceinline__ float fsigmoid(float x) { return 1.f / (1.f + __expf(-x)); }
__device__ __forceinline__ float ftanh(float x) {
    float ax = __builtin_fabsf(x);
    float e = __expf(-2.f * ax);
    float r = (1.f - e) / (1.f + e);
    return x < 0.f ? -r : r;
}
__device__ __forceinline__ void xg_store(float* p, float v) { *p = v; }
__device__ __forceinline__ void xg_store(ushort_t* p, float v) { *p = f2bf(v); }
__device__ __forceinline__ float4v xg_load4(const float4v* p) { return *p; }
__device__ __forceinline__ float4v xg_load4(const ushort4v* p) {
    ushort4v u = *p;
    float4v r = { bf2f(u[0]), bf2f(u[1]), bf2f(u[2]), bf2f(u[3]) };
    return r;
}
// async global->LDS 16B copy: LDS dest is wave-uniform base + lane*16
__device__ __forceinline__ void async_cp16(const ushort_t* g, ushort_t* s) {
    __builtin_amdgcn_global_load_lds(
        (const __attribute__((address_space(1))) uint32_t*)g,
        (__attribute__((address_space(3))) uint32_t*)s, 16, 0, 0);
}

// ---------------- prep: fp32->bf16 conversions (W_ih row-PERMUTED: r' = j*4+gate
// so k_gemm's natural output layout is gate-interleaved float4), zero h buffers,
// zero barrier counters.
__global__ __launch_bounds__(256) void k_prep(
    const float* __restrict__ feat, const float* __restrict__ wih,
    const float* __restrict__ whh,
    ushort_t* __restrict__ featb, ushort_t* __restrict__ wihb,
    ushort_t* __restrict__ whhb, ushort_t* __restrict__ hbuf,
    int* __restrict__ cnt)
{
    const size_t NF = (size_t)NB * NT * ND / 4;   // 8388608 float4 chunks
    const size_t NW = (size_t)NG * ND / 4;        // 1048576
    const size_t NHB = (size_t)2 * 65536 * 2 / 16; // 16384 16B chunks
    size_t total = NF + 2 * NW + NHB;
    size_t stride = (size_t)gridDim.x * blockDim.x;
    for (size_t i = (size_t)blockIdx.x * blockDim.x + threadIdx.x; i < total; i += stride) {
        if (i < NF) {
            float4v v = ((const float4v*)feat)[i];
            ushort4v o = { f2bf(v[0]), f2bf(v[1]), f2bf(v[2]), f2bf(v[3]) };
            ((ushort4v*)featb)[i] = o;
        } else if (i < NF + NW) {
            size_t j = i - NF;                      // chunk over [4096 rows][256 f4]
            size_t row = j >> 8, kc = j & 255;
            size_t rowp = ((row & 1023) << 2) | (row >> 10);   // j*4 + gate
            float4v v = ((const float4v*)wih)[j];
            ushort4v o = { f2bf(v[0]), f2bf(v[1]), f2bf(v[2]), f2bf(v[3]) };
            ((ushort4v*)wihb)[rowp * 256 + kc] = o;
        } else if (i < NF + 2 * NW) {
            size_t j = i - NF - NW;
            float4v v = ((const float4v*)whh)[j];
            ushort4v o = { f2bf(v[0]), f2bf(v[1]), f2bf(v[2]), f2bf(v[3]) };
            ((ushort4v*)whhb)[j] = o;
        } else {
            size_t j = i - NF - 2 * NW;
            uint4v z = { 0u, 0u, 0u, 0u };
            ((uint4v*)hbuf)[j] = z;
        }
    }
    // Zero the FULL 4096-int barrier region (16 blocks x 256 threads).
    if (blockIdx.x < 16) cnt[blockIdx.x * 256 + threadIdx.x] = 0;
}

// ---------------- x_gates GEMM: xg[t][b][rp] = feat[b,t,:] . Wih'[rp,:] + bias[rp]
// rp = j*4+gate (permuted). 128x128 tile, BK=64, 256 threads.
// m97-style: global_load_lds width-16 staging (no VGPR round-trip), 2-barrier
// K-loop. LDS chunk slot s holds global chunk (row=s>>3, kb=(s&7)^(row&7)) —
// XOR swizzle makes frag ds_read_b128 2-way banked (free) instead of 16-way.
template <typename XGT>
__global__ __launch_bounds__(256) void k_gemm(
    const ushort_t* __restrict__ Ab,   // feature bf16 [32768][1024]
    const ushort_t* __restrict__ Bb,   // W_ih' bf16 [4096][1024] (row-permuted)
    const float* __restrict__ bih, const float* __restrict__ bhh,
    const int* __restrict__ slenp, XGT* __restrict__ xg)
{
    int bid = blockIdx.x;                  // 8192 tiles
    int panel = bid >> 8;                  // 32 panels of (8 mt x 32 nt) for L2 reuse
    int qq = bid & 255;
    int mt = (panel << 3) | (qq & 7);
    int nt = qq >> 3;
    int m0 = mt << 7, n0 = nt << 7;
    int b = m0 >> 9;                       // 128-row tile lies within one batch
    int t0 = m0 & 511;
    int sl = slenp[b];
    if (t0 >= sl) return;                  // whole tile masked: xg never read there

    __shared__ short8 ldsA8[1024];         // 128 rows x 8 chunks (16 KB), swizzled
    __shared__ short8 ldsB8[1024];
    ushort_t* ldsA = (ushort_t*)ldsA8;
    ushort_t* ldsB = (ushort_t*)ldsB8;
    const ushort_t* gA = Ab + (size_t)m0 * 1024;
    const ushort_t* gB = Bb + (size_t)n0 * 1024;

    int tid = threadIdx.x;
    int wave = tid >> 6, lane = tid & 63;
    int wm = (wave >> 1) << 6;
    int wn = (wave & 1) << 6;
    int fl = lane & 15, fq = lane >> 4;

    f32x4 acc[4][4];
#pragma unroll
    for (int i = 0; i < 4; i++)
#pragma unroll
        for (int j = 0; j < 4; j++) { f32x4 z = {0.f, 0.f, 0.f, 0.f}; acc[i][j] = z; }

    // per-thread staging coords: slot s = u*256 + tid; row = s>>3, kb = (s&7)^(row&7)
    int srow_[4], skb_[4];
#pragma unroll
    for (int u = 0; u < 4; u++) {
        int s = u * 256 + tid;
        srow_[u] = s >> 3;
        skb_[u] = (s & 7) ^ (srow_[u] & 7);
    }

    for (int k0 = 0; k0 < 1024; k0 += 64) {
        if (k0) __syncthreads();           // protect LDS from previous iter's reads
#pragma unroll
        for (int u = 0; u < 4; u++) {
            // uniform LDS base (chunk u*256 + wave*64); lane lands at +lane*16B
            ushort_t* sa = ldsA + (size_t)(u * 256 + wave * 64) * 8;
            ushort_t* sb = ldsB + (size_t)(u * 256 + wave * 64) * 8;
            async_cp16(gA + (size_t)srow_[u] * 1024 + k0 + skb_[u] * 8, sa);
            async_cp16(gB + (size_t)srow_[u] * 1024 + k0 + skb_[u] * 8, sb);
        }
        __syncthreads();                   // drains vmcnt: LDS tiles ready
#pragma unroll
        for (int ks = 0; ks < 2; ks++) {
            int kc = ks * 4 + fq;          // 16B chunk within BK=64
            short8 af[4], bf[4];
#pragma unroll
            for (int i = 0; i < 4; i++) {
                int ra = wm + i * 16 + fl;
                int rb = wn + i * 16 + fl;
                af[i] = ldsA8[ra * 8 + (kc ^ (ra & 7))];
                bf[i] = ldsB8[rb * 8 + (kc ^ (rb & 7))];
            }
#pragma unroll
            for (int i = 0; i < 4; i++)
#pragma unroll
                for (int j = 0; j < 4; j++)
                    acc[i][j] = __builtin_amdgcn_mfma_f32_16x16x32_bf16(af[i], bf[j], acc[i][j], 0, 0, 0);
        }
    }
    // epilogue: C layout col=lane&15, row=quad*4+reg. Columns are permuted rows rp.
#pragma unroll
    for (int j = 0; j < 4; j++) {
        int rp = n0 + wn + j * 16 + fl;              // permuted row index
        int bi = ((rp & 3) << 10) | (rp >> 2);       // gate*1024 + j
        float bv = bih[bi] + bhh[bi];
#pragma unroll
        for (int i = 0; i < 4; i++) {
#pragma unroll
            for (int r = 0; r < 4; r++) {
                int m = wm + i * 16 + fq * 4 + r;
                int t = t0 + m;
                if (t < sl)
                    xg_store(&xg[((size_t)t * 64 + b) * 4096 + rp], acc[i][j][r] + bv);
            }
        }
    }
}

// ---------------- persistent recurrence kernel: 256 WGs x 256 thr
// WG = (mb: 16-batch block) x (j0: 16 h-columns). Wave ks = K-quarter for ALL 4
// gates. Batch blocks are INDEPENDENT chains -> 4 separate 64-WG barriers
// (8 subgroups x 8 -> root -> subflag broadcast; fan <=8 per line). Groups
// early-exit at blk_len and bulk-write the zero tail.
template <typename XG4>
__global__ __launch_bounds__(256, 1) void k_rec(
    const ushort_t* __restrict__ whhb, const XG4* __restrict__ xg4,
    const int* __restrict__ slenp, ushort_t* __restrict__ hbuf,
    float* __restrict__ out, int* __restrict__ cnt)
{
    const int tid = threadIdx.x;
    const int ks = tid >> 6, lane = tid & 63;      // wave = K-quarter
    const int wg = blockIdx.x;
    const int mb = wg >> 6;            // 0..3 batch block
    const int mem = wg & 63;           // member within group
    const int j0 = mem << 4;           // 16 j per WG
    const int nn = lane & 15, q = lane >> 4;

    // B-fragments: 4 gates x 16 j rows at K-quarter ks, resident in VGPRs (128)
    short8 wfrag[4][8];
    {
        const short8* w8 = (const short8*)whhb;
#pragma unroll
        for (int g = 0; g < 4; g++) {
            const short8* wp = w8 + (size_t)(g * NHH + j0 + nn) * 128 + ks * 32;
#pragma unroll
            for (int u = 0; u < 8; u++) wfrag[g][u] = wp[u * 4 + q];
        }
    }
    const int eb = tid >> 4, ej = tid & 15;
    const int b_g = (mb << 4) + eb;    // epilogue thread's (batch, j)
    const int j_g = j0 + ej;
    const int slen = slenp[b_g];
    const int blk_len = slenp[mb << 4]; // seq_len sorted desc -> block max
    const int ab = (mb << 4) + nn;     // A-frag batch row for this lane

    // per-mb barrier region: 512 ints. subcnt sg at [sg*16], root at [256],
    // subflag sg at [272 + sg*16].
    int* base    = cnt + mb * 512;
    int* subcnt  = base + (mem >> 3) * 16;
    int* root    = base + 256;
    int* subflag = base + 272 + (mem >> 3) * 16;
    const bool subleader = ((mem & 7) == 0);

    // ks-reduction buffer: [g][j 16][ks 4][b 16], j-stride 84 floats, ks-stride 20
    __shared__ float red[4 * 16 * 84];   // 21504 B

    float c_st = 0.f, h_st = 0.f, hv_prev = 0.f;
    float4v xv = { 0.f, 0.f, 0.f, 0.f };
    if (0 < slen) xv = xg_load4(&xg4[(size_t)b_g * 1024 + j_g]);   // xg(0)

#pragma unroll 1
    for (int t = 0; t < blk_len; ++t) {
        // deferred out store for t-1 (off critical path)
        if (t > 0) out[((size_t)b_g * NT + (t - 1)) * 1024 + j_g] = hv_prev;
        // prefetch xg(t+1): in flight across the whole gemm phase
        float4v nxv = { 0.f, 0.f, 0.f, 0.f };
        if (t + 1 < slen) nxv = xg_load4(&xg4[((size_t)(t + 1) * 64 + b_g) * 1024 + j_g]);

        const ull_t* hb8 = (const ull_t*)(hbuf + (size_t)(t & 1) * 65536);
        // A: 8 x 16B agent loads (disjoint K-quarter per wave)
        ull_t raw[16];
#pragma unroll
        for (int u = 0; u < 8; u++) {
            size_t ch = ((size_t)((ks * 32 + u * 4 + q) * 64 + ab)) * 2;
            raw[2 * u]     = __hip_atomic_load(&hb8[ch],     __ATOMIC_RELAXED, __HIP_MEMORY_SCOPE_AGENT);
            raw[2 * u + 1] = __hip_atomic_load(&hb8[ch + 1], __ATOMIC_RELAXED, __HIP_MEMORY_SCOPE_AGENT);
        }
        f32x4 acc[4];
#pragma unroll
        for (int g = 0; g < 4; g++) { f32x4 z = {0.f, 0.f, 0.f, 0.f}; acc[g] = z; }
#pragma unroll
        for (int u = 0; u < 8; u++) {
            ull2 p; p[0] = raw[2 * u]; p[1] = raw[2 * u + 1];
            short8 af = __builtin_bit_cast(short8, p);
#pragma unroll
            for (int g = 0; g < 4; g++)
                acc[g] = __builtin_amdgcn_mfma_f32_16x16x32_bf16(af, wfrag[g][u], acc[g], 0, 0, 0);
        }
        __syncthreads();   // red consumed last step
#pragma unroll
        for (int g = 0; g < 4; g++)
            *(f32x4*)&red[g * 1344 + nn * 84 + ks * 20 + q * 4] = acc[g];
        __syncthreads();

        float hv = 0.f;
        if (t < slen) {
            float s[4];
#pragma unroll
            for (int g = 0; g < 4; g++) {
                const float* rp = &red[g * 1344 + ej * 84 + eb];
                s[g] = (rp[0] + rp[20]) + (rp[40] + rp[60]);
            }
            float ip = s[0] + xv[0];
            float fp = s[1] + xv[1];
            float gp = s[2] + xv[2];
            float op = s[3] + xv[3];
            float i_s = fsigmoid(ip), f_s = fsigmoid(fp);
            float g_t = ftanh(gp), o_s = fsigmoid(op);
            float cn = __builtin_fmaf(f_s, c_st, i_s * g_t);
            c_st = cn;
            h_st = o_s * ftanh(cn);
            hv = h_st;
        }
        hv_prev = hv;
        // h store: device-scope fine-grained (visible at L3 once vmcnt drains)
        __hip_atomic_store(&hbuf[(size_t)((t + 1) & 1) * 65536 +
                                 (size_t)((j_g >> 3) * 64 + b_g) * 8 + (j_g & 7)],
                           f2bf(h_st), __ATOMIC_RELAXED, __HIP_MEMORY_SCOPE_AGENT);
        xv = nxv;
        if (t + 1 < blk_len) {
            // drain own vmem (h store must be at L3 before arrival)
            asm volatile("s_waitcnt vmcnt(0)" ::: "memory");
            __syncthreads();
            if (tid == 0) {
                int old = __hip_atomic_fetch_add(subcnt, 1, __ATOMIC_RELAXED, __HIP_MEMORY_SCOPE_AGENT);
                if ((old & 7) == 7)   // last arrival of this 8-WG subgroup this step
                    __hip_atomic_fetch_add(root, 1, __ATOMIC_RELAXED, __HIP_MEMORY_SCOPE_AGENT);
                const int target = (t + 1) << 3;   // root += 8 per step
                if (subleader) {
                    while (__hip_atomic_load(root, __ATOMIC_RELAXED, __HIP_MEMORY_SCOPE_AGENT) < target)
                        __builtin_amdgcn_s_sleep(2);
                    __hip_atomic_store(subflag, t + 1, __ATOMIC_RELAXED, __HIP_MEMORY_SCOPE_AGENT);
                } else {
                    while (__hip_atomic_load(subflag, __ATOMIC_RELAXED, __HIP_MEMORY_SCOPE_AGENT) < t + 1)
                        __builtin_amdgcn_s_sleep(2);
                }
            }
            __syncthreads();
        }
    }
    // tail: last h output + zero padding past blk_len (overlapped with other groups)
    out[((size_t)b_g * NT + (blk_len - 1)) * 1024 + j_g] = hv_prev;
    for (int t = blk_len; t < NT; ++t)
        out[((size_t)b_g * NT + t) * 1024 + j_g] = 0.f;
}

extern "C" void kernel_launch(void* const* d_in, const int* in_sizes, int n_in,
                              void* d_out, int out_size, void* d_ws, size_t ws_size,
                              hipStream_t stream)
{
    const float* feat = (const float*)d_in[0];
    const float* wih  = (const float*)d_in[1];
    const float* whh  = (const float*)d_in[2];
    const float* bih  = (const float*)d_in[3];
    const float* bhh  = (const float*)d_in[4];
    const int*   sl   = (const int*)d_in[5];
    float* out = (float*)d_out;
    char* ws = (char*)d_ws;

    size_t off = 0;
    auto take = [&](size_t bytes) -> size_t {
        size_t o = off; off += (bytes + 255) & ~(size_t)255; return o;
    };
    size_t o_featb = take((size_t)NB * NT * ND * 2);  // 64 MiB
    size_t o_wihb  = take((size_t)NG * ND * 2);       // 8 MiB
    size_t o_whhb  = take((size_t)NG * ND * 2);       // 8 MiB
    size_t o_hbuf  = take((size_t)2 * 65536 * 2);     // 256 KiB (2 bf16 h buffers)
    size_t o_cnt   = take(16384);                     // 4 per-mb barrier regions
    size_t o_xg    = off;

    ushort_t* featb = (ushort_t*)(ws + o_featb);
    ushort_t* wihb  = (ushort_t*)(ws + o_wihb);
    ushort_t* whhb  = (ushort_t*)(ws + o_whhb);
    ushort_t* hbuf  = (ushort_t*)(ws + o_hbuf);
    int* cnt        = (int*)(ws + o_cnt);

    k_prep<<<2048, 256, 0, stream>>>(feat, wih, whh, featb, wihb, whhb, hbuf, cnt);

    size_t xg_elems = (size_t)NT * NB * NG;
    bool f32xg = (o_xg + xg_elems * 4) <= ws_size;    // prefer fp32 xg for accuracy
    if (f32xg) {
        float* xg = (float*)(ws + o_xg);
        k_gemm<float><<<8192, 256, 0, stream>>>(featb, wihb, bih, bhh, sl, xg);
        k_rec<float4v><<<256, 256, 0, stream>>>(whhb, (const float4v*)xg, sl, hbuf, out, cnt);
    } else {
        ushort_t* xg = (ushort_t*)(ws + o_xg);
        k_gemm<ushort_t><<<8192, 256, 0, stream>>>(featb, wihb, bih, bhh, sl, xg);
        k_rec<ushort4v><<<256, 256, 0, stream>>>(whhb, (const ushort4v*)xg, sl, hbuf, out, cnt);
    }
}